// Round 1
// baseline (522.222 us; speedup 1.0000x reference)
//
#include <hip/hip_runtime.h>
#include <math.h>

// Problem shapes
constexpr int B = 4, H = 16, S = 1024, D = 256, P = 64;
constexpr long long N_ROWS = (long long)B * H * S;            // 65536
// Output segment offsets (floats, concatenated in return order)
constexpr long long OFF_RT = 0;                               // routing_scores
constexpr long long SZ_RT  = N_ROWS;                          // 65536
constexpr long long OFF_OR = OFF_RT + SZ_RT;                  // optimal_routes
constexpr long long SZ_OR  = N_ROWS * (long long)S;           // 67108864
constexpr long long OFF_TW = OFF_OR + SZ_OR;                  // transfer_weights
constexpr long long SZ_TW  = 16LL * 64 * 64;                  // 65536
constexpr long long OFF_PS = OFF_TW + SZ_TW;                  // pattern_scores
constexpr long long SZ_PS  = N_ROWS * (long long)P;           // 4194304

// ---------------------------------------------------------------------------
// Kernel 1: normalize patterns, fold in 1/TEMPERATURE = 10.
// 64 blocks x 64 threads (one wave per pattern row).
__global__ __launch_bounds__(64) void k_normalize(const float* __restrict__ pat,
                                                  float* __restrict__ pn) {
    int p    = blockIdx.x;
    int lane = threadIdx.x;                 // 0..63, covers 256 floats as float4
    const float4* src = (const float4*)(pat + (long long)p * D);
    float4 v = src[lane];
    float ss = v.x * v.x + v.y * v.y + v.z * v.z + v.w * v.w;
    #pragma unroll
    for (int m = 1; m < 64; m <<= 1) ss += __shfl_xor(ss, m, 64);
    float scale = 10.0f / fmaxf(sqrtf(ss), 1e-12f);
    v.x *= scale; v.y *= scale; v.z *= scale; v.w *= scale;
    float4* dst = (float4*)(pn + (long long)p * D);
    dst[lane] = v;
}

// ---------------------------------------------------------------------------
// Kernel 2: routing_scores = 1/1024 (constant) and transfer_weights copy.
// 512 blocks x 256 threads = 131072 threads.
__global__ __launch_bounds__(256) void k_small(const float* __restrict__ tw,
                                               float* __restrict__ out) {
    int i = blockIdx.x * 256 + threadIdx.x;
    if (i < (int)SZ_RT) {
        out[OFF_RT + i] = 0.0009765625f;            // 1/1024
    } else {
        int j = i - (int)SZ_RT;
        out[OFF_TW + j] = tw[j];
    }
}

// ---------------------------------------------------------------------------
// Kernel 3: optimal_routes[..., j] = -j/1024. 256 MB of float4 stores.
// 65536 blocks x 256 threads, one float4 per thread.
__global__ __launch_bounds__(256) void k_routes(float4* __restrict__ out) {
    long long i = (long long)blockIdx.x * 256 + threadIdx.x;
    int j0 = (int)((i << 2) & (S - 1));             // 1024-periodic, float4-aligned
    float b0 = (float)j0 * (-0.0009765625f);
    float4 v;
    v.x = b0;
    v.y = b0 - 0.0009765625f;
    v.z = b0 - 0.001953125f;
    v.w = b0 - 0.0029296875f;
    out[i] = v;
}

// ---------------------------------------------------------------------------
// Kernel 4: sims = states @ pn^T (K=256, N=64), softmax over N, write scores.
// Row-per-lane: each thread owns one state row, acc[64] in VGPRs.
// Pattern loads are wave-uniform -> expect s_load scalarization.
// 256 blocks x 256 threads = 65536 rows.
__global__ __launch_bounds__(256, 4) void k_gemm_softmax(
        const float* __restrict__ states,
        const float* __restrict__ pn,
        float* __restrict__ out_ps) {
    long long r = (long long)blockIdx.x * 256 + threadIdx.x;
    const float* srow = states + r * D;

    float acc[P];
    #pragma unroll
    for (int p = 0; p < P; ++p) acc[p] = 0.0f;

    #pragma unroll 1
    for (int kc = 0; kc < D; kc += 32) {
        float s[32];
        const float4* sp = (const float4*)(srow + kc);
        #pragma unroll
        for (int q = 0; q < 8; ++q) {
            float4 t = sp[q];
            s[q * 4 + 0] = t.x; s[q * 4 + 1] = t.y;
            s[q * 4 + 2] = t.z; s[q * 4 + 3] = t.w;
        }
        #pragma unroll
        for (int p = 0; p < P; ++p) {
            const float* pk = pn + p * D + kc;      // wave-uniform address
            #pragma unroll
            for (int k = 0; k < 32; ++k) {
                acc[p] = fmaf(s[k], pk[k], acc[p]);
            }
        }
    }

    // In-lane softmax over 64 logits
    float m = acc[0];
    #pragma unroll
    for (int p = 1; p < P; ++p) m = fmaxf(m, acc[p]);
    float sum = 0.0f;
    #pragma unroll
    for (int p = 0; p < P; ++p) {
        acc[p] = __expf(acc[p] - m);
        sum += acc[p];
    }
    float inv = 1.0f / sum;

    float4* dst = (float4*)(out_ps + r * P);
    #pragma unroll
    for (int q = 0; q < 16; ++q) {
        float4 v;
        v.x = acc[q * 4 + 0] * inv;
        v.y = acc[q * 4 + 1] * inv;
        v.z = acc[q * 4 + 2] * inv;
        v.w = acc[q * 4 + 3] * inv;
        dst[q] = v;
    }
}

// ---------------------------------------------------------------------------
extern "C" void kernel_launch(void* const* d_in, const int* in_sizes, int n_in,
                              void* d_out, int out_size, void* d_ws, size_t ws_size,
                              hipStream_t stream) {
    const float* states   = (const float*)d_in[0];   // (4,16,1024,256) fp32
    const float* patterns = (const float*)d_in[1];   // (64,256) fp32
    const float* transfer = (const float*)d_in[2];   // (16,64,64) fp32
    float* out = (float*)d_out;
    float* pn  = (float*)d_ws;                       // 64*256 floats = 64 KB

    k_normalize<<<dim3(P), dim3(64), 0, stream>>>(patterns, pn);

    k_small<<<dim3(512), dim3(256), 0, stream>>>(transfer, out);

    k_routes<<<dim3(65536), dim3(256), 0, stream>>>((float4*)(out + OFF_OR));

    k_gemm_softmax<<<dim3(256), dim3(256), 0, stream>>>(states, pn, out + OFF_PS);
}

// Round 2
// 400.883 us; speedup vs baseline: 1.3027x; 1.3027x over previous
//
#include <hip/hip_runtime.h>
#include <math.h>

// Problem shapes
constexpr int B = 4, H = 16, S = 1024, D = 256, P = 64;
constexpr long long N_ROWS = (long long)B * H * S;            // 65536
// Output segment offsets (floats, concatenated in return order)
constexpr long long OFF_RT = 0;                               // routing_scores
constexpr long long SZ_RT  = N_ROWS;                          // 65536
constexpr long long OFF_OR = OFF_RT + SZ_RT;                  // optimal_routes
constexpr long long SZ_OR  = N_ROWS * (long long)S;           // 67108864
constexpr long long OFF_TW = OFF_OR + SZ_OR;                  // transfer_weights
constexpr long long SZ_TW  = 16LL * 64 * 64;                  // 65536
constexpr long long OFF_PS = OFF_TW + SZ_TW;                  // pattern_scores

// ---------------------------------------------------------------------------
// Kernel 1: normalize patterns, fold in 1/TEMPERATURE = 10, and TRANSPOSE to
// pnT[k][p] (256 x 64) so each k-slice of all 64 patterns is contiguous
// (wave-uniform s_load_dwordx16 fodder for the GEMM).
__global__ __launch_bounds__(64) void k_normalize(const float* __restrict__ pat,
                                                  float* __restrict__ pnT) {
    int p    = blockIdx.x;
    int lane = threadIdx.x;                 // 0..63, covers 256 floats as float4
    const float4* src = (const float4*)(pat + (long long)p * D);
    float4 v = src[lane];
    float ss = v.x * v.x + v.y * v.y + v.z * v.z + v.w * v.w;
    #pragma unroll
    for (int m = 1; m < 64; m <<= 1) ss += __shfl_xor(ss, m, 64);
    float scale = 10.0f / fmaxf(sqrtf(ss), 1e-12f);
    int k = lane * 4;
    pnT[(k + 0) * P + p] = v.x * scale;
    pnT[(k + 1) * P + p] = v.y * scale;
    pnT[(k + 2) * P + p] = v.z * scale;
    pnT[(k + 3) * P + p] = v.w * scale;
}

// ---------------------------------------------------------------------------
// Kernel 2: routing_scores = 1/1024 (constant) and transfer_weights copy.
__global__ __launch_bounds__(256) void k_small(const float* __restrict__ tw,
                                               float* __restrict__ out) {
    int i = blockIdx.x * 256 + threadIdx.x;
    if (i < (int)SZ_RT) {
        out[OFF_RT + i] = 0.0009765625f;            // 1/1024
    } else {
        int j = i - (int)SZ_RT;
        out[OFF_TW + j] = tw[j];
    }
}

// ---------------------------------------------------------------------------
// Kernel 3: optimal_routes[..., j] = -j/1024. 256 MB of float4 stores.
__global__ __launch_bounds__(256) void k_routes(float4* __restrict__ out) {
    long long i = (long long)blockIdx.x * 256 + threadIdx.x;
    int j0 = (int)((i << 2) & (S - 1));             // 1024-periodic, float4-aligned
    float b0 = (float)j0 * (-0.0009765625f);
    float4 v;
    v.x = b0;
    v.y = b0 - 0.0009765625f;
    v.z = b0 - 0.001953125f;
    v.w = b0 - 0.0029296875f;
    out[i] = v;
}

// ---------------------------------------------------------------------------
// Kernel 4: sims = states @ pn^T (K=256, N=64), softmax over N.
// Row-per-thread, acc[64] in VGPRs. Patterns come from pnT[k][p] via
// wave-uniform scalar loads (SGPR operand on v_fmac_f32 -> zero VMEM cost).
// NO min-waves launch bound: occupancy is grid-limited (1 wave/SIMD), so the
// allocator gets the full 512-VGPR budget -> no spill (R0 lesson: cap 128
// spilled acc[] to scratch, 60 MB of spill writes).
__global__ __launch_bounds__(256) void k_gemm_softmax(
        const float* __restrict__ states,
        const float* __restrict__ pnT,
        float* __restrict__ out_ps) {
    long long r = (long long)blockIdx.x * 256 + threadIdx.x;
    const float4* __restrict__ srow = (const float4*)(states + r * (long long)D);

    float acc[P];
    #pragma unroll
    for (int p = 0; p < P; ++p) acc[p] = 0.0f;

    float4 nxt = srow[0];
    #pragma unroll 1
    for (int c = 0; c < D / 4; ++c) {               // 64 chunks of 4 k-values
        float4 cur = nxt;
        if (c < D / 4 - 1) nxt = srow[c + 1];       // prefetch next state chunk
        const float* __restrict__ pk = pnT + c * 4 * P;   // wave-uniform base
        #pragma unroll
        for (int p = 0; p < P; ++p) {
            float a = acc[p];
            a = fmaf(cur.x, pk[p],         a);
            a = fmaf(cur.y, pk[P + p],     a);
            a = fmaf(cur.z, pk[2 * P + p], a);
            a = fmaf(cur.w, pk[3 * P + p], a);
            acc[p] = a;
        }
    }

    // In-lane softmax over 64 logits
    float m = acc[0];
    #pragma unroll
    for (int p = 1; p < P; ++p) m = fmaxf(m, acc[p]);
    float sum = 0.0f;
    #pragma unroll
    for (int p = 0; p < P; ++p) {
        acc[p] = __expf(acc[p] - m);
        sum += acc[p];
    }
    float inv = 1.0f / sum;

    float4* dst = (float4*)(out_ps + r * P);
    #pragma unroll
    for (int q = 0; q < 16; ++q) {
        float4 v;
        v.x = acc[q * 4 + 0] * inv;
        v.y = acc[q * 4 + 1] * inv;
        v.z = acc[q * 4 + 2] * inv;
        v.w = acc[q * 4 + 3] * inv;
        dst[q] = v;
    }
}

// ---------------------------------------------------------------------------
extern "C" void kernel_launch(void* const* d_in, const int* in_sizes, int n_in,
                              void* d_out, int out_size, void* d_ws, size_t ws_size,
                              hipStream_t stream) {
    const float* states   = (const float*)d_in[0];   // (4,16,1024,256) fp32
    const float* patterns = (const float*)d_in[1];   // (64,256) fp32
    const float* transfer = (const float*)d_in[2];   // (16,64,64) fp32
    float* out = (float*)d_out;
    float* pnT = (float*)d_ws;                       // 256*64 floats = 64 KB

    k_normalize<<<dim3(P), dim3(64), 0, stream>>>(patterns, pnT);

    k_small<<<dim3(512), dim3(256), 0, stream>>>(transfer, out);

    k_routes<<<dim3(65536), dim3(256), 0, stream>>>((float4*)(out + OFF_OR));

    k_gemm_softmax<<<dim3(256), dim3(256), 0, stream>>>(states, pnT, out + OFF_PS);
}

// Round 3
// 345.509 us; speedup vs baseline: 1.5115x; 1.1603x over previous
//
#include <hip/hip_runtime.h>
#include <math.h>

// Problem shapes
constexpr int B = 4, H = 16, S = 1024, D = 256, P = 64;
constexpr long long N_ROWS = (long long)B * H * S;            // 65536
// Output segment offsets (floats, concatenated in return order)
constexpr long long OFF_RT = 0;                               // routing_scores
constexpr long long SZ_RT  = N_ROWS;                          // 65536
constexpr long long OFF_OR = OFF_RT + SZ_RT;                  // optimal_routes
constexpr long long SZ_OR  = N_ROWS * (long long)S;           // 67108864
constexpr long long OFF_TW = OFF_OR + SZ_OR;                  // transfer_weights
constexpr long long SZ_TW  = 16LL * 64 * 64;                  // 65536
constexpr long long OFF_PS = OFF_TW + SZ_TW;                  // pattern_scores

typedef _Float16 half8  __attribute__((ext_vector_type(8)));
typedef _Float16 half4v __attribute__((ext_vector_type(4)));
typedef float    floatx4 __attribute__((ext_vector_type(4)));

// ---------------------------------------------------------------------------
// Kernel 1: normalize patterns, fold in 1/TEMPERATURE = 10, split each value
// into f16 hi + f16 lo (a = hi + lo, |lo| <= 2^-11 |a|) for split-precision
// MFMA. Layout [p][k] row-major (exactly what the B-fragment loads want).
__global__ __launch_bounds__(64) void k_normalize(const float* __restrict__ pat,
                                                  _Float16* __restrict__ pnh,
                                                  _Float16* __restrict__ pnl) {
    int p    = blockIdx.x;
    int lane = threadIdx.x;                 // 0..63, covers 256 floats as float4
    const float4* src = (const float4*)(pat + (long long)p * D);
    float4 v = src[lane];
    float ss = v.x * v.x + v.y * v.y + v.z * v.z + v.w * v.w;
    #pragma unroll
    for (int m = 1; m < 64; m <<= 1) ss += __shfl_xor(ss, m, 64);
    float scale = 10.0f / fmaxf(sqrtf(ss), 1e-12f);
    float a[4] = { v.x * scale, v.y * scale, v.z * scale, v.w * scale };
    half4v hh, ll;
    #pragma unroll
    for (int j = 0; j < 4; ++j) {
        _Float16 h = (_Float16)a[j];
        hh[j] = h;
        ll[j] = (_Float16)(a[j] - (float)h);
    }
    *(half4v*)(pnh + (long long)p * D + lane * 4) = hh;
    *(half4v*)(pnl + (long long)p * D + lane * 4) = ll;
}

// ---------------------------------------------------------------------------
// Kernel 2: routing_scores = 1/1024 (constant) and transfer_weights copy.
__global__ __launch_bounds__(256) void k_small(const float* __restrict__ tw,
                                               float* __restrict__ out) {
    int i = blockIdx.x * 256 + threadIdx.x;
    if (i < (int)SZ_RT) {
        out[OFF_RT + i] = 0.0009765625f;            // 1/1024
    } else {
        int j = i - (int)SZ_RT;
        out[OFF_TW + j] = tw[j];
    }
}

// ---------------------------------------------------------------------------
// Kernel 3: optimal_routes[..., j] = -j/1024. 256 MB of float4 stores (floor).
__global__ __launch_bounds__(256) void k_routes(float4* __restrict__ out) {
    long long i = (long long)blockIdx.x * 256 + threadIdx.x;
    int j0 = (int)((i << 2) & (S - 1));             // 1024-periodic, float4-aligned
    float b0 = (float)j0 * (-0.0009765625f);
    float4 v;
    v.x = b0;
    v.y = b0 - 0.0009765625f;
    v.z = b0 - 0.001953125f;
    v.w = b0 - 0.0029296875f;
    out[i] = v;
}

// ---------------------------------------------------------------------------
// Kernel 4: sims = states @ pn^T via f16 split-precision MFMA, then row
// softmax over 64 patterns.
//   Block = 256 thr = 4 waves; block tile = 64 rows; wave tile = 16 rows x 64.
//   Per wave: 8 K-steps x 4 N-tiles x 3 split MFMAs (16x16x32 f16) = 96 MFMAs.
//   A-frags: lane(q=lane>>4, m=lane&15) loads states[row0+m][kk*32+q*8 .. +8]
//   (fp32, 32 B contiguous), converts to hi/lo f16 in-register.
//   B-frags: B[k][n]=pn[n][k] -> lane loads pnh/pnl[t*16+m][kk*32+q*8 .. +8].
//   C/D layout: col = lane&15, row = (lane>>4)*4 + reg (guide §3, measured).
__global__ __launch_bounds__(256) void k_gemm_mfma(
        const float* __restrict__ states,
        const _Float16* __restrict__ pnh,
        const _Float16* __restrict__ pnl,
        float* __restrict__ out_ps) {
    int wave = threadIdx.x >> 6;
    int lane = threadIdx.x & 63;
    int q    = lane >> 4;                  // quad 0..3
    int m    = lane & 15;
    long long row0 = (long long)blockIdx.x * 64 + wave * 16;
    const float* __restrict__ arow = states + (row0 + m) * D + q * 8;

    floatx4 acc[4] = {floatx4{0,0,0,0}, floatx4{0,0,0,0},
                      floatx4{0,0,0,0}, floatx4{0,0,0,0}};

    #pragma unroll 2
    for (int kk = 0; kk < 8; ++kk) {
        float4 a0 = *(const float4*)(arow + kk * 32);
        float4 a1 = *(const float4*)(arow + kk * 32 + 4);
        float av[8] = { a0.x, a0.y, a0.z, a0.w, a1.x, a1.y, a1.z, a1.w };
        half8 ah, al;
        #pragma unroll
        for (int j = 0; j < 8; ++j) {
            _Float16 h = (_Float16)av[j];
            ah[j] = h;
            al[j] = (_Float16)(av[j] - (float)h);
        }
        #pragma unroll
        for (int t = 0; t < 4; ++t) {
            long long boff = (long long)(t * 16 + m) * D + kk * 32 + q * 8;
            half8 bh = *(const half8*)(pnh + boff);
            half8 bl = *(const half8*)(pnl + boff);
            acc[t] = __builtin_amdgcn_mfma_f32_16x16x32_f16(ah, bh, acc[t], 0, 0, 0);
            acc[t] = __builtin_amdgcn_mfma_f32_16x16x32_f16(al, bh, acc[t], 0, 0, 0);
            acc[t] = __builtin_amdgcn_mfma_f32_16x16x32_f16(ah, bl, acc[t], 0, 0, 0);
        }
    }

    // Row softmax: row = q*4 + r lives in the 16 lanes sharing q (masks 1..8
    // stay inside that group); each lane holds 4 cols of it (one per N-tile).
    float e[4][4];
    #pragma unroll
    for (int r = 0; r < 4; ++r) {
        float mx = fmaxf(fmaxf(acc[0][r], acc[1][r]), fmaxf(acc[2][r], acc[3][r]));
        #pragma unroll
        for (int msk = 1; msk < 16; msk <<= 1) mx = fmaxf(mx, __shfl_xor(mx, msk, 64));
        float s = 0.0f;
        #pragma unroll
        for (int t = 0; t < 4; ++t) { e[t][r] = __expf(acc[t][r] - mx); s += e[t][r]; }
        #pragma unroll
        for (int msk = 1; msk < 16; msk <<= 1) s += __shfl_xor(s, msk, 64);
        float inv = 1.0f / s;
        long long row = row0 + q * 4 + r;
        #pragma unroll
        for (int t = 0; t < 4; ++t) {
            out_ps[row * P + t * 16 + m] = e[t][r] * inv;
        }
    }
}

// ---------------------------------------------------------------------------
extern "C" void kernel_launch(void* const* d_in, const int* in_sizes, int n_in,
                              void* d_out, int out_size, void* d_ws, size_t ws_size,
                              hipStream_t stream) {
    const float* states   = (const float*)d_in[0];   // (4,16,1024,256) fp32
    const float* patterns = (const float*)d_in[1];   // (64,256) fp32
    const float* transfer = (const float*)d_in[2];   // (16,64,64) fp32
    float* out = (float*)d_out;
    _Float16* pnh = (_Float16*)d_ws;                 // 64*256 halves = 32 KB
    _Float16* pnl = pnh + P * D;                     // +32 KB

    k_normalize<<<dim3(P), dim3(64), 0, stream>>>(patterns, pnh, pnl);

    k_small<<<dim3(512), dim3(256), 0, stream>>>(transfer, out);

    k_routes<<<dim3(65536), dim3(256), 0, stream>>>((float4*)(out + OFF_OR));

    k_gemm_mfma<<<dim3(1024), dim3(256), 0, stream>>>(states, pnh, pnl, out + OFF_PS);
}